// Round 1
// baseline (1193.356 us; speedup 1.0000x reference)
//
#include <hip/hip_runtime.h>
#include <math.h>

#define N_NODES 20000
#define KNBR 32
#define DIM 128
#define EDIM 64
#define MDIM 192
#define HEADS 8
#define KSZ 16
#define VSZ 16
#define OUTD 128
#define FFD 512
#define LN_EPS 1e-5f

// ---------------------------------------------------------------------------
// K1: x = LN(node_rep)*mask  -> ws.x ;  q = x@Wq + bq -> ws.q
// block = 256 threads, 8 nodes/block. grid = 2500.
// ---------------------------------------------------------------------------
__global__ __launch_bounds__(256) void k1_ln_q(
    const float* __restrict__ node_rep, const float* __restrict__ mask,
    const float* __restrict__ ln1_s, const float* __restrict__ ln1_b,
    const float* __restrict__ Wq, const float* __restrict__ bq,
    float* __restrict__ xout, float* __restrict__ qout)
{
    __shared__ float xs[8][DIM];
    const int t = threadIdx.x;
    const int nb = blockIdx.x * 8;
    const int g = t >> 5;        // node slot within block (0..7)
    const int lane = t & 31;     // 32 lanes x 4 elems = 128
    const int node = nb + g;

    float4 v = reinterpret_cast<const float4*>(node_rep + (size_t)node * DIM)[lane];
    float s1 = v.x + v.y + v.z + v.w;
    float s2 = v.x * v.x + v.y * v.y + v.z * v.z + v.w * v.w;
    #pragma unroll
    for (int off = 16; off; off >>= 1) {
        s1 += __shfl_xor(s1, off, 32);
        s2 += __shfl_xor(s2, off, 32);
    }
    const float mean = s1 * (1.0f / DIM);
    const float var  = s2 * (1.0f / DIM) - mean * mean;
    const float rs   = rsqrtf(var + LN_EPS);
    const float mk   = mask[node];

    float4 sc = reinterpret_cast<const float4*>(ln1_s)[lane];
    float4 of = reinterpret_cast<const float4*>(ln1_b)[lane];
    float4 xo;
    xo.x = ((v.x - mean) * rs * sc.x + of.x) * mk;
    xo.y = ((v.y - mean) * rs * sc.y + of.y) * mk;
    xo.z = ((v.z - mean) * rs * sc.z + of.z) * mk;
    xo.w = ((v.w - mean) * rs * sc.w + of.w) * mk;
    reinterpret_cast<float4*>(xout + (size_t)node * DIM)[lane] = xo;
    const int c0 = lane * 4;
    xs[g][c0 + 0] = xo.x; xs[g][c0 + 1] = xo.y;
    xs[g][c0 + 2] = xo.z; xs[g][c0 + 3] = xo.w;
    __syncthreads();

    // q: 8 nodes x 128 cols = 1024 outputs; thread t does 4 (node stride 2)
    const int col = t & 127;
    const int n0  = t >> 7;      // 0 or 1
    float acc[4] = {0.f, 0.f, 0.f, 0.f};
    for (int d = 0; d < DIM; ++d) {
        const float w = Wq[d * DIM + col];
        #pragma unroll
        for (int i = 0; i < 4; ++i) acc[i] += xs[n0 + 2 * i][d] * w;
    }
    const float b = bq[col];
    #pragma unroll
    for (int i = 0; i < 4; ++i)
        qout[(size_t)(nb + n0 + 2 * i) * DIM + col] = acc[i] + b;
}

// ---------------------------------------------------------------------------
// K2: per-node attention. block = 256 threads, 1 node/block. grid = 20000.
//   gather neigh[32][192] (x[senders] ++ edge_feat) into LDS,
//   kk|vv = neigh @ [Wk|Wv] + [bk|bv]   (chunked over k-dim, W staged in LDS)
//   logits -> softmax -> o = attn @ vv  -> ws.o
// ---------------------------------------------------------------------------
__global__ __launch_bounds__(256) void k2_attn(
    const float* __restrict__ xg, const float* __restrict__ qg,
    const float* __restrict__ edge_feat,
    const float* __restrict__ Wk, const float* __restrict__ bk,
    const float* __restrict__ Wv, const float* __restrict__ bv,
    const int* __restrict__ senders,
    float* __restrict__ og)
{
    __shared__ float ng[KNBR][200];      // neigh, padded stride
    __shared__ float wc[32][256];        // k-chunk of [Wk | Wv]
    __shared__ float qs[DIM];
    __shared__ int   snd[KNBR];
    __shared__ float lp[KNBR][16];       // logit partials
    __shared__ float attn_s[HEADS][KNBR];
    __shared__ float op[8][DIM];         // o partials per row-group

    const int t = threadIdx.x;
    const int n = blockIdx.x;

    if (t < KNBR) snd[t] = senders[n * KNBR + t];
    if (t >= 128) qs[t - 128] = qg[(size_t)n * DIM + (t - 128)];
    __syncthreads();

    // gather: 32 rows x 48 float4 (32 node-feat + 16 edge-feat)
    for (int idx = t; idx < KNBR * 48; idx += 256) {
        const int k = idx / 48, j = idx - k * 48;
        float4 v;
        if (j < 32)
            v = reinterpret_cast<const float4*>(xg + (size_t)snd[k] * DIM)[j];
        else
            v = reinterpret_cast<const float4*>(edge_feat + ((size_t)n * KNBR + k) * EDIM)[j - 32];
        *reinterpret_cast<float4*>(&ng[k][j * 4]) = v;
    }

    const int cg = t & 31;       // col group: cols 8cg..8cg+7 of [kk|vv]
    const int rg = t >> 5;       // row group: rows 4rg..4rg+3
    const int cg8 = cg * 8, rg4 = rg * 4;
    float acc[4][8];
    #pragma unroll
    for (int r = 0; r < 4; ++r)
        #pragma unroll
        for (int j = 0; j < 8; ++j) acc[r][j] = 0.f;

    for (int ch = 0; ch < 6; ++ch) {
        __syncthreads();   // protect wc reuse (and gather on first iter)
        // stage W chunk: rows ch*32..+31 of Wk|Wv -> wc[32][256]
        for (int idx = t; idx < 2048; idx += 256) {
            const int kk = idx >> 6, j = idx & 63;
            const float* srcw = (j < 32)
                ? (Wk + (size_t)(ch * 32 + kk) * DIM + j * 4)
                : (Wv + (size_t)(ch * 32 + kk) * DIM + (j - 32) * 4);
            *reinterpret_cast<float4*>(&wc[kk][j * 4]) =
                *reinterpret_cast<const float4*>(srcw);
        }
        __syncthreads();
        const int ch32 = ch * 32;
        for (int kt = 0; kt < 32; kt += 4) {
            float4 a[4];
            #pragma unroll
            for (int r = 0; r < 4; ++r)
                a[r] = *reinterpret_cast<const float4*>(&ng[rg4 + r][ch32 + kt]);
            #pragma unroll
            for (int kk = 0; kk < 4; ++kk) {
                const float4 w0 = *reinterpret_cast<const float4*>(&wc[kt + kk][cg8]);
                const float4 w1 = *reinterpret_cast<const float4*>(&wc[kt + kk][cg8 + 4]);
                #pragma unroll
                for (int r = 0; r < 4; ++r) {
                    const float ar = reinterpret_cast<const float*>(&a[r])[kk];
                    acc[r][0] += ar * w0.x; acc[r][1] += ar * w0.y;
                    acc[r][2] += ar * w0.z; acc[r][3] += ar * w0.w;
                    acc[r][4] += ar * w1.x; acc[r][5] += ar * w1.y;
                    acc[r][6] += ar * w1.z; acc[r][7] += ar * w1.w;
                }
            }
        }
    }

    // bias
    #pragma unroll
    for (int j = 0; j < 8; ++j) {
        const int cc = cg8 + j;
        const float b = (cc < 128) ? bk[cc] : bv[cc - 128];
        #pragma unroll
        for (int r = 0; r < 4; ++r) acc[r][j] += b;
    }

    // logit partials (kk half): head h = cg>>1, two partials per (nb,h)
    if (cg < 16) {
        #pragma unroll
        for (int r = 0; r < 4; ++r) {
            float p = 0.f;
            #pragma unroll
            for (int j = 0; j < 8; ++j) p += qs[cg8 + j] * acc[r][j];
            lp[rg4 + r][cg] = p;
        }
    }
    __syncthreads();

    // softmax: one 32-lane group per head
    {
        const int h = t >> 5, nbi = t & 31;
        float lg = (lp[nbi][h * 2] + lp[nbi][h * 2 + 1]) * 0.25f;
        float mx = lg;
        #pragma unroll
        for (int off = 16; off; off >>= 1) mx = fmaxf(mx, __shfl_xor(mx, off, 32));
        const float e = __expf(lg - mx);
        float s = e;
        #pragma unroll
        for (int off = 16; off; off >>= 1) s += __shfl_xor(s, off, 32);
        attn_s[h][nbi] = e / s;
    }
    __syncthreads();

    // o partials (vv half)
    if (cg >= 16) {
        const int h = (cg - 16) >> 1;
        float s[8];
        #pragma unroll
        for (int j = 0; j < 8; ++j) s[j] = 0.f;
        #pragma unroll
        for (int r = 0; r < 4; ++r) {
            const float at = attn_s[h][rg4 + r];
            #pragma unroll
            for (int j = 0; j < 8; ++j) s[j] += at * acc[r][j];
        }
        #pragma unroll
        for (int j = 0; j < 8; ++j) op[rg][(cg - 16) * 8 + j] = s[j];
    }
    __syncthreads();

    if (t < 128) {
        float s = 0.f;
        #pragma unroll
        for (int r = 0; r < 8; ++r) s += op[r][t];
        og[(size_t)n * DIM + t] = s;
    }
}

// ---------------------------------------------------------------------------
// K3: res = o@Wo+bo; *mask; LN2; t1=relu(res@W1+b1); f=t1@W2+b2; *mask;
//     out = x + f.   block = 256 threads, 32 nodes/block. grid = 625.
// ---------------------------------------------------------------------------
__global__ __launch_bounds__(256) void k3_ffn(
    const float* __restrict__ og, const float* __restrict__ xg,
    const float* __restrict__ mask,
    const float* __restrict__ Wo, const float* __restrict__ bo,
    const float* __restrict__ ln2_s, const float* __restrict__ ln2_b,
    const float* __restrict__ W1, const float* __restrict__ b1,
    const float* __restrict__ W2, const float* __restrict__ b2,
    float* __restrict__ outp)
{
    __shared__ float os[32][DIM];
    __shared__ float hs[32][DIM];
    __shared__ float ts[32][FFD];

    const int t = threadIdx.x;
    const int nb = blockIdx.x * 32;
    const int cg = t & 31, rg = t >> 5;
    const int rg4 = rg * 4;

    for (int idx = t; idx < 32 * 32; idx += 256) {
        const int r = idx >> 5, j = idx & 31;
        reinterpret_cast<float4*>(&os[r][0])[j] =
            reinterpret_cast<const float4*>(og + (size_t)(nb + r) * DIM)[j];
    }
    __syncthreads();

    // res = o @ Wo : thread tile 4 rows x 4 cols (cols 4cg..4cg+3)
    float a2[4][4];
    #pragma unroll
    for (int r = 0; r < 4; ++r)
        #pragma unroll
        for (int j = 0; j < 4; ++j) a2[r][j] = 0.f;
    for (int d = 0; d < DIM; ++d) {
        const float4 w = *reinterpret_cast<const float4*>(Wo + d * DIM + cg * 4);
        #pragma unroll
        for (int r = 0; r < 4; ++r) {
            const float a = os[rg4 + r][d];
            a2[r][0] += a * w.x; a2[r][1] += a * w.y;
            a2[r][2] += a * w.z; a2[r][3] += a * w.w;
        }
    }
    const float4 bo4 = reinterpret_cast<const float4*>(bo)[cg];
    const float4 s4  = reinterpret_cast<const float4*>(ln2_s)[cg];
    const float4 f4  = reinterpret_cast<const float4*>(ln2_b)[cg];
    #pragma unroll
    for (int r = 0; r < 4; ++r) {
        const float mk = mask[nb + rg4 + r];
        a2[r][0] = (a2[r][0] + bo4.x) * mk;
        a2[r][1] = (a2[r][1] + bo4.y) * mk;
        a2[r][2] = (a2[r][2] + bo4.z) * mk;
        a2[r][3] = (a2[r][3] + bo4.w) * mk;
        // LN2 across the row (reduce over 32 cg lanes)
        float s1 = a2[r][0] + a2[r][1] + a2[r][2] + a2[r][3];
        float s2 = a2[r][0]*a2[r][0] + a2[r][1]*a2[r][1]
                 + a2[r][2]*a2[r][2] + a2[r][3]*a2[r][3];
        #pragma unroll
        for (int off = 16; off; off >>= 1) {
            s1 += __shfl_xor(s1, off, 32);
            s2 += __shfl_xor(s2, off, 32);
        }
        const float mean = s1 * (1.0f / OUTD);
        const float var  = s2 * (1.0f / OUTD) - mean * mean;
        const float rs   = rsqrtf(var + LN_EPS);
        float4 hv;
        hv.x = (a2[r][0] - mean) * rs * s4.x + f4.x;
        hv.y = (a2[r][1] - mean) * rs * s4.y + f4.y;
        hv.z = (a2[r][2] - mean) * rs * s4.z + f4.z;
        hv.w = (a2[r][3] - mean) * rs * s4.w + f4.w;
        *reinterpret_cast<float4*>(&hs[rg4 + r][cg * 4]) = hv;
    }
    __syncthreads();

    // t1 = relu(h @ W1 + b1): cols cg + 32m (stride-32 interleave, conflict-free)
    float a3[4][16];
    #pragma unroll
    for (int r = 0; r < 4; ++r)
        #pragma unroll
        for (int m = 0; m < 16; ++m) a3[r][m] = 0.f;
    for (int d = 0; d < DIM; ++d) {
        float av[4];
        #pragma unroll
        for (int r = 0; r < 4; ++r) av[r] = hs[rg4 + r][d];
        #pragma unroll
        for (int m = 0; m < 16; ++m) {
            const float w = W1[d * FFD + cg + 32 * m];
            #pragma unroll
            for (int r = 0; r < 4; ++r) a3[r][m] += av[r] * w;
        }
    }
    #pragma unroll
    for (int m = 0; m < 16; ++m) {
        const float b = b1[cg + 32 * m];
        #pragma unroll
        for (int r = 0; r < 4; ++r)
            ts[rg4 + r][cg + 32 * m] = fmaxf(a3[r][m] + b, 0.f);
    }
    __syncthreads();

    // f = t1 @ W2 + b2 : thread tile 4 rows x 4 cols
    float a4[4][4];
    #pragma unroll
    for (int r = 0; r < 4; ++r)
        #pragma unroll
        for (int j = 0; j < 4; ++j) a4[r][j] = 0.f;
    for (int d = 0; d < FFD; ++d) {
        const float4 w = *reinterpret_cast<const float4*>(W2 + d * OUTD + cg * 4);
        #pragma unroll
        for (int r = 0; r < 4; ++r) {
            const float a = ts[rg4 + r][d];
            a4[r][0] += a * w.x; a4[r][1] += a * w.y;
            a4[r][2] += a * w.z; a4[r][3] += a * w.w;
        }
    }
    const float4 b2v = reinterpret_cast<const float4*>(b2)[cg];
    #pragma unroll
    for (int r = 0; r < 4; ++r) {
        const int node = nb + rg4 + r;
        const float mk = mask[node];
        const float4 xr = reinterpret_cast<const float4*>(xg + (size_t)node * DIM)[cg];
        float4 o;
        o.x = xr.x + (a4[r][0] + b2v.x) * mk;
        o.y = xr.y + (a4[r][1] + b2v.y) * mk;
        o.z = xr.z + (a4[r][2] + b2v.z) * mk;
        o.w = xr.w + (a4[r][3] + b2v.w) * mk;
        reinterpret_cast<float4*>(outp + (size_t)node * DIM)[cg] = o;
    }
}

// ---------------------------------------------------------------------------
extern "C" void kernel_launch(void* const* d_in, const int* in_sizes, int n_in,
                              void* d_out, int out_size, void* d_ws, size_t ws_size,
                              hipStream_t stream)
{
    const float* node_rep = (const float*)d_in[0];
    const float* mask     = (const float*)d_in[1];
    const float* edge_feat= (const float*)d_in[2];
    const float* Wq = (const float*)d_in[3];
    const float* bq = (const float*)d_in[4];
    const float* Wk = (const float*)d_in[5];
    const float* bk = (const float*)d_in[6];
    const float* Wv = (const float*)d_in[7];
    const float* bv = (const float*)d_in[8];
    const float* Wo = (const float*)d_in[9];
    const float* bo = (const float*)d_in[10];
    const float* ln1_s = (const float*)d_in[11];
    const float* ln1_b = (const float*)d_in[12];
    const float* ln2_s = (const float*)d_in[13];
    const float* ln2_b = (const float*)d_in[14];
    const float* W1 = (const float*)d_in[15];
    const float* b1 = (const float*)d_in[16];
    const float* W2 = (const float*)d_in[17];
    const float* b2 = (const float*)d_in[18];
    const int* senders = (const int*)d_in[19];

    float* out = (float*)d_out;
    float* xg = (float*)d_ws;                         // [N,128] f32
    float* qg = xg + (size_t)N_NODES * DIM;           // [N,128]
    float* og = qg + (size_t)N_NODES * DIM;           // [N,128]

    hipLaunchKernelGGL(k1_ln_q, dim3(N_NODES / 8), dim3(256), 0, stream,
                       node_rep, mask, ln1_s, ln1_b, Wq, bq, xg, qg);
    hipLaunchKernelGGL(k2_attn, dim3(N_NODES), dim3(256), 0, stream,
                       xg, qg, edge_feat, Wk, bk, Wv, bv, senders, og);
    hipLaunchKernelGGL(k3_ffn, dim3(N_NODES / 32), dim3(256), 0, stream,
                       og, xg, mask, Wo, bo, ln2_s, ln2_b, W1, b1, W2, b2, out);
}

// Round 2
// 443.823 us; speedup vs baseline: 2.6888x; 2.6888x over previous
//
#include <hip/hip_runtime.h>
#include <math.h>

#define N_NODES 20000
#define KNBR 32
#define DIM 128
#define EDIM 64
#define HEADS 8
#define OUTD 128
#define FFD 512
#define LN_EPS 1e-5f

typedef __attribute__((ext_vector_type(8))) short short8v;
typedef __attribute__((ext_vector_type(4))) float f32x4;

__device__ __forceinline__ unsigned short f2bf(float f) {
    unsigned u = __builtin_bit_cast(unsigned, f);
    u += 0x7fffu + ((u >> 16) & 1u);
    return (unsigned short)(u >> 16);
}
__device__ __forceinline__ float bfhi2f(unsigned u_hi16) {  // bf16 in high 16 bits
    return __builtin_bit_cast(float, u_hi16);
}

// ---------------------------------------------------------------------------
// K0: WkvT[c][k] = [Wk|Wv][(128+k)][c]  as bf16, c=0..255, k=0..63
// ---------------------------------------------------------------------------
__global__ __launch_bounds__(256) void k0_prep(
    const float* __restrict__ Wk, const float* __restrict__ Wv,
    unsigned short* __restrict__ WkvT)
{
    const int idx = blockIdx.x * 256 + threadIdx.x;   // 16384 total
    const int c = idx >> 6, k = idx & 63;
    const float v = (c < 128) ? Wk[(size_t)(128 + k) * 128 + c]
                              : Wv[(size_t)(128 + k) * 128 + (c - 128)];
    WkvT[c * 64 + k] = f2bf(v);
}

// ---------------------------------------------------------------------------
// K1: x = LN(node_rep)*mask -> xout ; q = x@Wq+bq -> qout ;
//     P = x@[Wk_x|Wv_x] + [bk|bv] -> Pp (bf16, MFMA-col-packed layout)
// Pp layout: Pp[n*256 + g*64 + d*4 + j] = P[n][(4g+j)*16 + d]
// block 256, 8 nodes/block, grid 2500.
// ---------------------------------------------------------------------------
__global__ __launch_bounds__(256) void k1_ln_q_p(
    const float* __restrict__ node_rep, const float* __restrict__ mask,
    const float* __restrict__ ln1_s, const float* __restrict__ ln1_b,
    const float* __restrict__ Wq, const float* __restrict__ bq,
    const float* __restrict__ Wk, const float* __restrict__ bk,
    const float* __restrict__ Wv, const float* __restrict__ bv,
    float* __restrict__ xout, float* __restrict__ qout,
    unsigned short* __restrict__ Pp)
{
    __shared__ float xs[8][DIM];
    const int t = threadIdx.x;
    const int nb = blockIdx.x * 8;
    const int g = t >> 5;
    const int lane = t & 31;
    const int node = nb + g;

    float4 v = reinterpret_cast<const float4*>(node_rep + (size_t)node * DIM)[lane];
    float s1 = v.x + v.y + v.z + v.w;
    float s2 = v.x * v.x + v.y * v.y + v.z * v.z + v.w * v.w;
    #pragma unroll
    for (int off = 16; off; off >>= 1) {
        s1 += __shfl_xor(s1, off, 32);
        s2 += __shfl_xor(s2, off, 32);
    }
    const float mean = s1 * (1.0f / DIM);
    const float var  = s2 * (1.0f / DIM) - mean * mean;
    const float rs   = rsqrtf(var + LN_EPS);
    const float mk   = mask[node];

    float4 sc = reinterpret_cast<const float4*>(ln1_s)[lane];
    float4 of = reinterpret_cast<const float4*>(ln1_b)[lane];
    float4 xo;
    xo.x = ((v.x - mean) * rs * sc.x + of.x) * mk;
    xo.y = ((v.y - mean) * rs * sc.y + of.y) * mk;
    xo.z = ((v.z - mean) * rs * sc.z + of.z) * mk;
    xo.w = ((v.w - mean) * rs * sc.w + of.w) * mk;
    reinterpret_cast<float4*>(xout + (size_t)node * DIM)[lane] = xo;
    const int c0 = lane * 4;
    xs[g][c0 + 0] = xo.x; xs[g][c0 + 1] = xo.y;
    xs[g][c0 + 2] = xo.z; xs[g][c0 + 3] = xo.w;
    __syncthreads();

    // q: col = t&127, nodes n0, n0+2, n0+4, n0+6
    const int col = t & 127;
    const int n0  = t >> 7;
    // P: c = t (0..255), all 8 nodes
    const int c = t;
    const float* wq = Wq + col;
    const float* wp = (c < 128) ? (Wk + c) : (Wv + (c - 128));

    float accq[4] = {0.f, 0.f, 0.f, 0.f};
    float accp[8] = {0.f, 0.f, 0.f, 0.f, 0.f, 0.f, 0.f, 0.f};
    for (int d = 0; d < DIM; ++d) {
        const float wqd = wq[(size_t)d * 128];
        const float wpd = wp[(size_t)d * 128];
        #pragma unroll
        for (int i = 0; i < 4; ++i) accq[i] += xs[n0 + 2 * i][d] * wqd;
        #pragma unroll
        for (int i = 0; i < 8; ++i) accp[i] += xs[i][d] * wpd;
    }
    const float bqv = bq[col];
    #pragma unroll
    for (int i = 0; i < 4; ++i)
        qout[(size_t)(nb + n0 + 2 * i) * DIM + col] = accq[i] + bqv;

    const float bpv = (c < 128) ? bk[c] : bv[c - 128];
    const int pos = (c >> 6) * 64 + (c & 15) * 4 + ((c >> 4) & 3);
    #pragma unroll
    for (int i = 0; i < 8; ++i)
        Pp[(size_t)(nb + i) * 256 + pos] = f2bf(accp[i] + bpv);
}

// ---------------------------------------------------------------------------
// K2: per-node attention via MFMA. 1 wave = 1 node, 4 nodes/block, no LDS.
//   E = edge[n] (32x64) @ WkvT^T  via mfma_f32_16x16x32_bf16 (2r x 16c x 2s)
//   kk|vv = E + P[snd]  (packed bf16 gather)
//   logits/softmax/PV via in-wave shuffles.
// ---------------------------------------------------------------------------
__global__ __launch_bounds__(256, 2) void k2_attn(
    const float* __restrict__ qg, const float* __restrict__ edge_feat,
    const unsigned short* __restrict__ Pp,
    const unsigned short* __restrict__ WkvT,
    const int* __restrict__ senders,
    float* __restrict__ og)
{
    const int t = threadIdx.x;
    const int w = t >> 6, l = t & 63;
    const int n = blockIdx.x * 4 + w;
    const int l15 = l & 15, lg = l >> 4;

    const int snd0 = senders[n * KNBR + (l & 31)];
    const float qa = qg[(size_t)n * DIM + l];
    const float qb = qg[(size_t)n * DIM + 64 + l];

    f32x4 acc[2][16];
    #pragma unroll
    for (int r = 0; r < 2; ++r)
        #pragma unroll
        for (int cc = 0; cc < 16; ++cc)
            acc[r][cc] = (f32x4){0.f, 0.f, 0.f, 0.f};

    // A fragments: edge rows, f32 -> bf16
    short8v afr[2][2];
    #pragma unroll
    for (int r = 0; r < 2; ++r) {
        #pragma unroll
        for (int s = 0; s < 2; ++s) {
            const float* ep = edge_feat
                + ((size_t)n * KNBR + 16 * r + l15) * EDIM + s * 32 + lg * 8;
            const float4 e0 = *reinterpret_cast<const float4*>(ep);
            const float4 e1 = *reinterpret_cast<const float4*>(ep + 4);
            short8v a;
            a[0] = (short)f2bf(e0.x); a[1] = (short)f2bf(e0.y);
            a[2] = (short)f2bf(e0.z); a[3] = (short)f2bf(e0.w);
            a[4] = (short)f2bf(e1.x); a[5] = (short)f2bf(e1.y);
            a[6] = (short)f2bf(e1.z); a[7] = (short)f2bf(e1.w);
            afr[r][s] = a;
        }
    }

    // MFMA: acc[r][c] += A[r][s] * B[c][s]
    #pragma unroll
    for (int cc = 0; cc < 16; ++cc) {
        #pragma unroll
        for (int s = 0; s < 2; ++s) {
            const short8v b = *reinterpret_cast<const short8v*>(
                WkvT + (size_t)(16 * cc + l15) * EDIM + s * 32 + lg * 8);
            acc[0][cc] = __builtin_amdgcn_mfma_f32_16x16x32_bf16(
                afr[0][s], b, acc[0][cc], 0, 0, 0);
            acc[1][cc] = __builtin_amdgcn_mfma_f32_16x16x32_bf16(
                afr[1][s], b, acc[1][cc], 0, 0, 0);
        }
    }

    // P gather & add: lane element (r, i) lives at row = 16r + lg*4 + i, col 16c+l15
    #pragma unroll
    for (int r = 0; r < 2; ++r) {
        #pragma unroll
        for (int i = 0; i < 4; ++i) {
            const int row = 16 * r + lg * 4 + i;
            const int sr = __shfl(snd0, row, 64);
            const unsigned short* pp = Pp + (size_t)sr * 256 + l15 * 4;
            #pragma unroll
            for (int g = 0; g < 4; ++g) {
                const uint2 u = *reinterpret_cast<const uint2*>(pp + g * 64);
                acc[r][g * 4 + 0][i] += bfhi2f(u.x << 16);
                acc[r][g * 4 + 1][i] += bfhi2f(u.x & 0xffff0000u);
                acc[r][g * 4 + 2][i] += bfhi2f(u.y << 16);
                acc[r][g * 4 + 3][i] += bfhi2f(u.y & 0xffff0000u);
            }
        }
    }

    // epilogue per head: logits -> softmax -> PV
    #pragma unroll
    for (int h = 0; h < 8; ++h) {
        const float qv = __shfl((h < 4) ? qa : qb, (h & 3) * 16 + l15, 64);
        float tm[8];
        #pragma unroll
        for (int r = 0; r < 2; ++r)
            #pragma unroll
            for (int i = 0; i < 4; ++i)
                tm[r * 4 + i] = acc[r][h][i] * qv;
        #pragma unroll
        for (int off = 1; off <= 8; off <<= 1) {
            #pragma unroll
            for (int k = 0; k < 8; ++k)
                tm[k] += __shfl_xor(tm[k], off, 64);
        }
        float m = tm[0];
        #pragma unroll
        for (int k = 1; k < 8; ++k) m = fmaxf(m, tm[k]);
        m = fmaxf(m, __shfl_xor(m, 16, 64));
        m = fmaxf(m, __shfl_xor(m, 32, 64));
        float s = 0.f, at[8];
        #pragma unroll
        for (int k = 0; k < 8; ++k) {
            at[k] = __expf((tm[k] - m) * 0.25f);
            s += at[k];
        }
        s += __shfl_xor(s, 16, 64);
        s += __shfl_xor(s, 32, 64);
        const float inv = 1.0f / s;
        float ov = 0.f;
        #pragma unroll
        for (int r = 0; r < 2; ++r)
            #pragma unroll
            for (int i = 0; i < 4; ++i)
                ov += at[r * 4 + i] * acc[r][8 + h][i];
        ov *= inv;
        ov += __shfl_xor(ov, 16, 64);
        ov += __shfl_xor(ov, 32, 64);
        if (lg == 0)
            og[(size_t)n * DIM + h * 16 + l15] = ov;
    }
}

// ---------------------------------------------------------------------------
// K3: res = o@Wo+bo; *mask; LN2; t1=relu(res@W1+b1); f=t1@W2+b2; *mask;
//     out = x + f.   block 256, 32 nodes/block, grid 625.  (unchanged)
// ---------------------------------------------------------------------------
__global__ __launch_bounds__(256) void k3_ffn(
    const float* __restrict__ og, const float* __restrict__ xg,
    const float* __restrict__ mask,
    const float* __restrict__ Wo, const float* __restrict__ bo,
    const float* __restrict__ ln2_s, const float* __restrict__ ln2_b,
    const float* __restrict__ W1, const float* __restrict__ b1,
    const float* __restrict__ W2, const float* __restrict__ b2,
    float* __restrict__ outp)
{
    __shared__ float os[32][DIM];
    __shared__ float hs[32][DIM];
    __shared__ float ts[32][FFD];

    const int t = threadIdx.x;
    const int nb = blockIdx.x * 32;
    const int cg = t & 31, rg = t >> 5;
    const int rg4 = rg * 4;

    for (int idx = t; idx < 32 * 32; idx += 256) {
        const int r = idx >> 5, j = idx & 31;
        reinterpret_cast<float4*>(&os[r][0])[j] =
            reinterpret_cast<const float4*>(og + (size_t)(nb + r) * DIM)[j];
    }
    __syncthreads();

    float a2[4][4];
    #pragma unroll
    for (int r = 0; r < 4; ++r)
        #pragma unroll
        for (int j = 0; j < 4; ++j) a2[r][j] = 0.f;
    for (int d = 0; d < DIM; ++d) {
        const float4 w = *reinterpret_cast<const float4*>(Wo + (size_t)d * DIM + cg * 4);
        #pragma unroll
        for (int r = 0; r < 4; ++r) {
            const float a = os[rg4 + r][d];
            a2[r][0] += a * w.x; a2[r][1] += a * w.y;
            a2[r][2] += a * w.z; a2[r][3] += a * w.w;
        }
    }
    const float4 bo4 = reinterpret_cast<const float4*>(bo)[cg];
    const float4 s4  = reinterpret_cast<const float4*>(ln2_s)[cg];
    const float4 f4  = reinterpret_cast<const float4*>(ln2_b)[cg];
    #pragma unroll
    for (int r = 0; r < 4; ++r) {
        const float mk = mask[nb + rg4 + r];
        a2[r][0] = (a2[r][0] + bo4.x) * mk;
        a2[r][1] = (a2[r][1] + bo4.y) * mk;
        a2[r][2] = (a2[r][2] + bo4.z) * mk;
        a2[r][3] = (a2[r][3] + bo4.w) * mk;
        float s1 = a2[r][0] + a2[r][1] + a2[r][2] + a2[r][3];
        float s2 = a2[r][0]*a2[r][0] + a2[r][1]*a2[r][1]
                 + a2[r][2]*a2[r][2] + a2[r][3]*a2[r][3];
        #pragma unroll
        for (int off = 16; off; off >>= 1) {
            s1 += __shfl_xor(s1, off, 32);
            s2 += __shfl_xor(s2, off, 32);
        }
        const float mean = s1 * (1.0f / OUTD);
        const float var  = s2 * (1.0f / OUTD) - mean * mean;
        const float rs   = rsqrtf(var + LN_EPS);
        float4 hv;
        hv.x = (a2[r][0] - mean) * rs * s4.x + f4.x;
        hv.y = (a2[r][1] - mean) * rs * s4.y + f4.y;
        hv.z = (a2[r][2] - mean) * rs * s4.z + f4.z;
        hv.w = (a2[r][3] - mean) * rs * s4.w + f4.w;
        *reinterpret_cast<float4*>(&hs[rg4 + r][cg * 4]) = hv;
    }
    __syncthreads();

    float a3[4][16];
    #pragma unroll
    for (int r = 0; r < 4; ++r)
        #pragma unroll
        for (int m2 = 0; m2 < 16; ++m2) a3[r][m2] = 0.f;
    for (int d = 0; d < DIM; ++d) {
        float av[4];
        #pragma unroll
        for (int r = 0; r < 4; ++r) av[r] = hs[rg4 + r][d];
        #pragma unroll
        for (int m2 = 0; m2 < 16; ++m2) {
            const float w = W1[(size_t)d * FFD + cg + 32 * m2];
            #pragma unroll
            for (int r = 0; r < 4; ++r) a3[r][m2] += av[r] * w;
        }
    }
    #pragma unroll
    for (int m2 = 0; m2 < 16; ++m2) {
        const float b = b1[cg + 32 * m2];
        #pragma unroll
        for (int r = 0; r < 4; ++r)
            ts[rg4 + r][cg + 32 * m2] = fmaxf(a3[r][m2] + b, 0.f);
    }
    __syncthreads();

    float a4[4][4];
    #pragma unroll
    for (int r = 0; r < 4; ++r)
        #pragma unroll
        for (int j = 0; j < 4; ++j) a4[r][j] = 0.f;
    for (int d = 0; d < FFD; ++d) {
        const float4 w = *reinterpret_cast<const float4*>(W2 + (size_t)d * OUTD + cg * 4);
        #pragma unroll
        for (int r = 0; r < 4; ++r) {
            const float a = ts[rg4 + r][d];
            a4[r][0] += a * w.x; a4[r][1] += a * w.y;
            a4[r][2] += a * w.z; a4[r][3] += a * w.w;
        }
    }
    const float4 b2v = reinterpret_cast<const float4*>(b2)[cg];
    #pragma unroll
    for (int r = 0; r < 4; ++r) {
        const int node = nb + rg4 + r;
        const float mk = mask[node];
        const float4 xr = reinterpret_cast<const float4*>(xg + (size_t)node * DIM)[cg];
        float4 o;
        o.x = xr.x + (a4[r][0] + b2v.x) * mk;
        o.y = xr.y + (a4[r][1] + b2v.y) * mk;
        o.z = xr.z + (a4[r][2] + b2v.z) * mk;
        o.w = xr.w + (a4[r][3] + b2v.w) * mk;
        reinterpret_cast<float4*>(outp + (size_t)node * DIM)[cg] = o;
    }
}

// ---------------------------------------------------------------------------
extern "C" void kernel_launch(void* const* d_in, const int* in_sizes, int n_in,
                              void* d_out, int out_size, void* d_ws, size_t ws_size,
                              hipStream_t stream)
{
    const float* node_rep = (const float*)d_in[0];
    const float* mask     = (const float*)d_in[1];
    const float* edge_feat= (const float*)d_in[2];
    const float* Wq = (const float*)d_in[3];
    const float* bq = (const float*)d_in[4];
    const float* Wk = (const float*)d_in[5];
    const float* bk = (const float*)d_in[6];
    const float* Wv = (const float*)d_in[7];
    const float* bv = (const float*)d_in[8];
    const float* Wo = (const float*)d_in[9];
    const float* bo = (const float*)d_in[10];
    const float* ln1_s = (const float*)d_in[11];
    const float* ln1_b = (const float*)d_in[12];
    const float* ln2_s = (const float*)d_in[13];
    const float* ln2_b = (const float*)d_in[14];
    const float* W1 = (const float*)d_in[15];
    const float* b1 = (const float*)d_in[16];
    const float* W2 = (const float*)d_in[17];
    const float* b2 = (const float*)d_in[18];
    const int* senders = (const int*)d_in[19];

    float* out = (float*)d_out;
    float* xg = (float*)d_ws;                           // [N,128] f32
    float* qg = xg + (size_t)N_NODES * DIM;             // [N,128] f32
    float* og = qg + (size_t)N_NODES * DIM;             // [N,128] f32
    unsigned short* Pp   = (unsigned short*)(og + (size_t)N_NODES * DIM);  // [N,256] bf16
    unsigned short* WkvT = Pp + (size_t)N_NODES * 256;  // [256,64] bf16

    hipLaunchKernelGGL(k0_prep, dim3(64), dim3(256), 0, stream, Wk, Wv, WkvT);
    hipLaunchKernelGGL(k1_ln_q_p, dim3(N_NODES / 8), dim3(256), 0, stream,
                       node_rep, mask, ln1_s, ln1_b, Wq, bq, Wk, bk, Wv, bv,
                       xg, qg, Pp);
    hipLaunchKernelGGL(k2_attn, dim3(N_NODES / 4), dim3(256), 0, stream,
                       qg, edge_feat, Pp, WkvT, senders, og);
    hipLaunchKernelGGL(k3_ffn, dim3(N_NODES / 32), dim3(256), 0, stream,
                       og, xg, mask, Wo, bo, ln2_s, ln2_b, W1, b1, W2, b2, out);
}

// Round 3
// 317.730 us; speedup vs baseline: 3.7559x; 1.3969x over previous
//
#include <hip/hip_runtime.h>
#include <math.h>

#define N_NODES 20000
#define KNBR 32
#define DIM 128
#define EDIM 64
#define HEADS 8
#define OUTD 128
#define FFD 512
#define LN_EPS 1e-5f

typedef __attribute__((ext_vector_type(8))) short short8v;
typedef __attribute__((ext_vector_type(4))) float f32x4;

__device__ __forceinline__ unsigned short f2bf(float f) {
    unsigned u = __builtin_bit_cast(unsigned, f);
    u += 0x7fffu + ((u >> 16) & 1u);
    return (unsigned short)(u >> 16);
}
__device__ __forceinline__ float bfhi2f(unsigned u_hi16) {  // bf16 in high 16 bits
    return __builtin_bit_cast(float, u_hi16);
}

// ---------------------------------------------------------------------------
// K0: weight prep (bf16, B-fragment-friendly transposed layouts)
//   WkvT[c][k] = [Wk|Wv][128+k][c]        (256 x 64)
//   WoT [c][d] = Wo[d][c]                 (128 x 128)
//   W1T [f][d] = W1[d][f]                 (512 x 128)
//   W2T [c][f] = W2[f][c]                 (128 x 512)
// ---------------------------------------------------------------------------
__global__ __launch_bounds__(256) void k0_prep(
    const float* __restrict__ Wk, const float* __restrict__ Wv,
    const float* __restrict__ Wo, const float* __restrict__ W1,
    const float* __restrict__ W2,
    unsigned short* __restrict__ WkvT, unsigned short* __restrict__ WoT,
    unsigned short* __restrict__ W1T, unsigned short* __restrict__ W2T)
{
    const int idx = blockIdx.x * 256 + threadIdx.x;   // 163840 total
    if (idx < 16384) {
        const int c = idx >> 6, k = idx & 63;
        WkvT[idx] = f2bf((c < 128) ? Wk[(size_t)(128 + k) * 128 + c]
                                   : Wv[(size_t)(128 + k) * 128 + (c - 128)]);
    } else if (idx < 32768) {
        const int j = idx - 16384, c = j >> 7, d = j & 127;
        WoT[j] = f2bf(Wo[(size_t)d * 128 + c]);
    } else if (idx < 98304) {
        const int j = idx - 32768, f = j >> 7, d = j & 127;
        W1T[j] = f2bf(W1[(size_t)d * 512 + f]);
    } else {
        const int j = idx - 98304, c = j >> 9, f = j & 511;
        W2T[j] = f2bf(W2[(size_t)f * 128 + c]);
    }
}

// ---------------------------------------------------------------------------
// K1: x = LN(node_rep)*mask -> xout ; q = x@Wq+bq -> qout ;
//     P = x@[Wk_x|Wv_x] + [bk|bv] -> Pp (bf16, MFMA-col-packed layout)
// Pp layout: Pp[n*256 + g*64 + d*4 + j] = P[n][(4g+j)*16 + d]
// ---------------------------------------------------------------------------
__global__ __launch_bounds__(256) void k1_ln_q_p(
    const float* __restrict__ node_rep, const float* __restrict__ mask,
    const float* __restrict__ ln1_s, const float* __restrict__ ln1_b,
    const float* __restrict__ Wq, const float* __restrict__ bq,
    const float* __restrict__ Wk, const float* __restrict__ bk,
    const float* __restrict__ Wv, const float* __restrict__ bv,
    float* __restrict__ xout, float* __restrict__ qout,
    unsigned short* __restrict__ Pp)
{
    __shared__ float xs[8][DIM];
    const int t = threadIdx.x;
    const int nb = blockIdx.x * 8;
    const int g = t >> 5;
    const int lane = t & 31;
    const int node = nb + g;

    float4 v = reinterpret_cast<const float4*>(node_rep + (size_t)node * DIM)[lane];
    float s1 = v.x + v.y + v.z + v.w;
    float s2 = v.x * v.x + v.y * v.y + v.z * v.z + v.w * v.w;
    #pragma unroll
    for (int off = 16; off; off >>= 1) {
        s1 += __shfl_xor(s1, off, 32);
        s2 += __shfl_xor(s2, off, 32);
    }
    const float mean = s1 * (1.0f / DIM);
    const float var  = s2 * (1.0f / DIM) - mean * mean;
    const float rs   = rsqrtf(var + LN_EPS);
    const float mk   = mask[node];

    float4 sc = reinterpret_cast<const float4*>(ln1_s)[lane];
    float4 of = reinterpret_cast<const float4*>(ln1_b)[lane];
    float4 xo;
    xo.x = ((v.x - mean) * rs * sc.x + of.x) * mk;
    xo.y = ((v.y - mean) * rs * sc.y + of.y) * mk;
    xo.z = ((v.z - mean) * rs * sc.z + of.z) * mk;
    xo.w = ((v.w - mean) * rs * sc.w + of.w) * mk;
    reinterpret_cast<float4*>(xout + (size_t)node * DIM)[lane] = xo;
    const int c0 = lane * 4;
    xs[g][c0 + 0] = xo.x; xs[g][c0 + 1] = xo.y;
    xs[g][c0 + 2] = xo.z; xs[g][c0 + 3] = xo.w;
    __syncthreads();

    const int col = t & 127;
    const int n0  = t >> 7;
    const int c = t;
    const float* wq = Wq + col;
    const float* wp = (c < 128) ? (Wk + c) : (Wv + (c - 128));

    float accq[4] = {0.f, 0.f, 0.f, 0.f};
    float accp[8] = {0.f, 0.f, 0.f, 0.f, 0.f, 0.f, 0.f, 0.f};
    for (int d = 0; d < DIM; ++d) {
        const float wqd = wq[(size_t)d * 128];
        const float wpd = wp[(size_t)d * 128];
        #pragma unroll
        for (int i = 0; i < 4; ++i) accq[i] += xs[n0 + 2 * i][d] * wqd;
        #pragma unroll
        for (int i = 0; i < 8; ++i) accp[i] += xs[i][d] * wpd;
    }
    const float bqv = bq[col];
    #pragma unroll
    for (int i = 0; i < 4; ++i)
        qout[(size_t)(nb + n0 + 2 * i) * DIM + col] = accq[i] + bqv;

    const float bpv = (c < 128) ? bk[c] : bv[c - 128];
    const int pos = (c >> 6) * 64 + (c & 15) * 4 + ((c >> 4) & 3);
    #pragma unroll
    for (int i = 0; i < 8; ++i)
        Pp[(size_t)(nb + i) * 256 + pos] = f2bf(accp[i] + bpv);
}

// ---------------------------------------------------------------------------
// K2: per-node attention via MFMA. 1 wave = 1 node, 4 nodes/block, no LDS.
// ---------------------------------------------------------------------------
__global__ __launch_bounds__(256, 2) void k2_attn(
    const float* __restrict__ qg, const float* __restrict__ edge_feat,
    const unsigned short* __restrict__ Pp,
    const unsigned short* __restrict__ WkvT,
    const int* __restrict__ senders,
    float* __restrict__ og)
{
    const int t = threadIdx.x;
    const int w = t >> 6, l = t & 63;
    const int n = blockIdx.x * 4 + w;
    const int l15 = l & 15, lg = l >> 4;

    const int snd0 = senders[n * KNBR + (l & 31)];
    const float qa = qg[(size_t)n * DIM + l];
    const float qb = qg[(size_t)n * DIM + 64 + l];

    f32x4 acc[2][16];
    #pragma unroll
    for (int r = 0; r < 2; ++r)
        #pragma unroll
        for (int cc = 0; cc < 16; ++cc)
            acc[r][cc] = (f32x4){0.f, 0.f, 0.f, 0.f};

    short8v afr[2][2];
    #pragma unroll
    for (int r = 0; r < 2; ++r) {
        #pragma unroll
        for (int s = 0; s < 2; ++s) {
            const float* ep = edge_feat
                + ((size_t)n * KNBR + 16 * r + l15) * EDIM + s * 32 + lg * 8;
            const float4 e0 = *reinterpret_cast<const float4*>(ep);
            const float4 e1 = *reinterpret_cast<const float4*>(ep + 4);
            short8v a;
            a[0] = (short)f2bf(e0.x); a[1] = (short)f2bf(e0.y);
            a[2] = (short)f2bf(e0.z); a[3] = (short)f2bf(e0.w);
            a[4] = (short)f2bf(e1.x); a[5] = (short)f2bf(e1.y);
            a[6] = (short)f2bf(e1.z); a[7] = (short)f2bf(e1.w);
            afr[r][s] = a;
        }
    }

    #pragma unroll
    for (int cc = 0; cc < 16; ++cc) {
        #pragma unroll
        for (int s = 0; s < 2; ++s) {
            const short8v b = *reinterpret_cast<const short8v*>(
                WkvT + (size_t)(16 * cc + l15) * EDIM + s * 32 + lg * 8);
            acc[0][cc] = __builtin_amdgcn_mfma_f32_16x16x32_bf16(
                afr[0][s], b, acc[0][cc], 0, 0, 0);
            acc[1][cc] = __builtin_amdgcn_mfma_f32_16x16x32_bf16(
                afr[1][s], b, acc[1][cc], 0, 0, 0);
        }
    }

    #pragma unroll
    for (int r = 0; r < 2; ++r) {
        #pragma unroll
        for (int i = 0; i < 4; ++i) {
            const int row = 16 * r + lg * 4 + i;
            const int sr = __shfl(snd0, row, 64);
            const unsigned short* pp = Pp + (size_t)sr * 256 + l15 * 4;
            #pragma unroll
            for (int g = 0; g < 4; ++g) {
                const uint2 u = *reinterpret_cast<const uint2*>(pp + g * 64);
                acc[r][g * 4 + 0][i] += bfhi2f(u.x << 16);
                acc[r][g * 4 + 1][i] += bfhi2f(u.x & 0xffff0000u);
                acc[r][g * 4 + 2][i] += bfhi2f(u.y << 16);
                acc[r][g * 4 + 3][i] += bfhi2f(u.y & 0xffff0000u);
            }
        }
    }

    #pragma unroll
    for (int h = 0; h < 8; ++h) {
        const float qv = __shfl((h < 4) ? qa : qb, (h & 3) * 16 + l15, 64);
        float tm[8];
        #pragma unroll
        for (int r = 0; r < 2; ++r)
            #pragma unroll
            for (int i = 0; i < 4; ++i)
                tm[r * 4 + i] = acc[r][h][i] * qv;
        #pragma unroll
        for (int off = 1; off <= 8; off <<= 1) {
            #pragma unroll
            for (int k = 0; k < 8; ++k)
                tm[k] += __shfl_xor(tm[k], off, 64);
        }
        float m = tm[0];
        #pragma unroll
        for (int k = 1; k < 8; ++k) m = fmaxf(m, tm[k]);
        m = fmaxf(m, __shfl_xor(m, 16, 64));
        m = fmaxf(m, __shfl_xor(m, 32, 64));
        float s = 0.f, at[8];
        #pragma unroll
        for (int k = 0; k < 8; ++k) {
            at[k] = __expf((tm[k] - m) * 0.25f);
            s += at[k];
        }
        s += __shfl_xor(s, 16, 64);
        s += __shfl_xor(s, 32, 64);
        const float inv = 1.0f / s;
        float ov = 0.f;
        #pragma unroll
        for (int r = 0; r < 2; ++r)
            #pragma unroll
            for (int i = 0; i < 4; ++i)
                ov += at[r * 4 + i] * acc[r][8 + h][i];
        ov *= inv;
        ov += __shfl_xor(ov, 16, 64);
        ov += __shfl_xor(ov, 32, 64);
        if (lg == 0)
            og[(size_t)n * DIM + h * 16 + l15] = ov;
    }
}

// ---------------------------------------------------------------------------
// K3 (MFMA): res=o@Wo+bo; *mask; LN2 (in C-frag regs); h->LDS(bf16,swizzled);
//   chunked FF: t=relu(h@W1+b1) chunk->LDS; acc3 += t@W2 ; +b2,*mask,+x -> out
// 64 nodes/block (4 waves x 16 rows), grid 313. LDS 32KB.
// XOR swizzle: byte ^= (row&7)<<4  (G4 fix for 256B-stride row-major bf16)
// ---------------------------------------------------------------------------
__device__ __forceinline__ void lds_wr16(unsigned short* base, int row, int col,
                                         unsigned short v) {
    const int byte = row * 256 + (((col * 2) ^ ((row & 7) << 4)));
    *reinterpret_cast<unsigned short*>(reinterpret_cast<char*>(base) + byte) = v;
}
__device__ __forceinline__ short8v lds_rd128(const unsigned short* base, int row,
                                             int colbyte) {
    const int byte = row * 256 + ((colbyte) ^ ((row & 7) << 4));
    return *reinterpret_cast<const short8v*>(
        reinterpret_cast<const char*>(base) + byte);
}

__global__ __launch_bounds__(256) void k3_ffn(
    const float* __restrict__ og, const float* __restrict__ xg,
    const float* __restrict__ mask,
    const unsigned short* __restrict__ WoT, const float* __restrict__ bo,
    const float* __restrict__ ln2_s, const float* __restrict__ ln2_b,
    const unsigned short* __restrict__ W1T, const float* __restrict__ b1,
    const unsigned short* __restrict__ W2T, const float* __restrict__ b2,
    float* __restrict__ outp)
{
    __shared__ unsigned short hls[64 * 128];
    __shared__ unsigned short tls[64 * 128];

    const int t = threadIdx.x;
    const int w = t >> 6, l = t & 63;
    const int l15 = l & 15, lg = l >> 4;
    const int nb = blockIdx.x * 64;
    const int arow = w * 16 + l15;          // LDS row for A-fragment reads
    const int anode = nb + arow;            // global node for A-operand loads
    const int r0 = lg * 4;                  // C-fragment row-sub base

    float mk[4];
    #pragma unroll
    for (int i = 0; i < 4; ++i) {
        const int node = nb + w * 16 + r0 + i;
        mk[i] = (node < N_NODES) ? mask[node] : 0.f;
    }

    // ---- GEMM1: res = o @ Wo (K=128) ----
    f32x4 acc1[8];
    #pragma unroll
    for (int ct = 0; ct < 8; ++ct) acc1[ct] = (f32x4){0.f, 0.f, 0.f, 0.f};
    #pragma unroll
    for (int kc = 0; kc < 4; ++kc) {
        short8v afr = {0, 0, 0, 0, 0, 0, 0, 0};
        if (anode < N_NODES) {
            const float* op = og + (size_t)anode * DIM + kc * 32 + lg * 8;
            const float4 e0 = *reinterpret_cast<const float4*>(op);
            const float4 e1 = *reinterpret_cast<const float4*>(op + 4);
            afr[0] = (short)f2bf(e0.x); afr[1] = (short)f2bf(e0.y);
            afr[2] = (short)f2bf(e0.z); afr[3] = (short)f2bf(e0.w);
            afr[4] = (short)f2bf(e1.x); afr[5] = (short)f2bf(e1.y);
            afr[6] = (short)f2bf(e1.z); afr[7] = (short)f2bf(e1.w);
        }
        #pragma unroll
        for (int ct = 0; ct < 8; ++ct) {
            const short8v b = *reinterpret_cast<const short8v*>(
                WoT + (size_t)(ct * 16 + l15) * DIM + kc * 32 + lg * 8);
            acc1[ct] = __builtin_amdgcn_mfma_f32_16x16x32_bf16(afr, b, acc1[ct], 0, 0, 0);
        }
    }

    // ---- +bo, *mask, LN2 in C-frag registers ----
    float s1[4] = {0.f, 0.f, 0.f, 0.f}, s2[4] = {0.f, 0.f, 0.f, 0.f};
    #pragma unroll
    for (int ct = 0; ct < 8; ++ct) {
        const float bov = bo[ct * 16 + l15];
        #pragma unroll
        for (int i = 0; i < 4; ++i) {
            const float v2 = (acc1[ct][i] + bov) * mk[i];
            acc1[ct][i] = v2;
            s1[i] += v2; s2[i] += v2 * v2;
        }
    }
    #pragma unroll
    for (int off = 1; off <= 8; off <<= 1) {
        #pragma unroll
        for (int i = 0; i < 4; ++i) {
            s1[i] += __shfl_xor(s1[i], off, 64);
            s2[i] += __shfl_xor(s2[i], off, 64);
        }
    }
    float mean[4], rsv[4];
    #pragma unroll
    for (int i = 0; i < 4; ++i) {
        mean[i] = s1[i] * (1.0f / OUTD);
        const float var = s2[i] * (1.0f / OUTD) - mean[i] * mean[i];
        rsv[i] = rsqrtf(var + LN_EPS);
    }
    #pragma unroll
    for (int ct = 0; ct < 8; ++ct) {
        const int col = ct * 16 + l15;
        const float sc = ln2_s[col], ofs = ln2_b[col];
        #pragma unroll
        for (int i = 0; i < 4; ++i) {
            const float h = (acc1[ct][i] - mean[i]) * rsv[i] * sc + ofs;
            lds_wr16(hls, w * 16 + r0 + i, col, f2bf(h));
        }
    }
    __syncthreads();

    short8v hfr[4];
    #pragma unroll
    for (int kc = 0; kc < 4; ++kc)
        hfr[kc] = lds_rd128(hls, arow, kc * 64 + lg * 16);

    // ---- FF chunks: t = relu(h@W1+b1) ; acc3 += t@W2 ----
    f32x4 acc3[8];
    #pragma unroll
    for (int ct = 0; ct < 8; ++ct) acc3[ct] = (f32x4){0.f, 0.f, 0.f, 0.f};

    for (int chunk = 0; chunk < 4; ++chunk) {
        f32x4 acc2[8];
        #pragma unroll
        for (int ct = 0; ct < 8; ++ct) acc2[ct] = (f32x4){0.f, 0.f, 0.f, 0.f};
        #pragma unroll
        for (int kc = 0; kc < 4; ++kc) {
            #pragma unroll
            for (int ct = 0; ct < 8; ++ct) {
                const short8v b = *reinterpret_cast<const short8v*>(
                    W1T + (size_t)(chunk * 128 + ct * 16 + l15) * DIM + kc * 32 + lg * 8);
                acc2[ct] = __builtin_amdgcn_mfma_f32_16x16x32_bf16(hfr[kc], b, acc2[ct], 0, 0, 0);
            }
        }
        #pragma unroll
        for (int ct = 0; ct < 8; ++ct) {
            const float bv = b1[chunk * 128 + ct * 16 + l15];
            #pragma unroll
            for (int i = 0; i < 4; ++i) {
                const float tv = fmaxf(acc2[ct][i] + bv, 0.f);
                lds_wr16(tls, w * 16 + r0 + i, ct * 16 + l15, f2bf(tv));
            }
        }
        __syncthreads();
        #pragma unroll
        for (int kc = 0; kc < 4; ++kc) {
            const short8v tfr = lds_rd128(tls, arow, kc * 64 + lg * 16);
            #pragma unroll
            for (int ct = 0; ct < 8; ++ct) {
                const short8v b = *reinterpret_cast<const short8v*>(
                    W2T + (size_t)(ct * 16 + l15) * FFD + chunk * 128 + kc * 32 + lg * 8);
                acc3[ct] = __builtin_amdgcn_mfma_f32_16x16x32_bf16(tfr, b, acc3[ct], 0, 0, 0);
            }
        }
        __syncthreads();
    }

    // ---- epilogue: f = (acc3 + b2)*mask ; out = x + f ----
    #pragma unroll
    for (int ct = 0; ct < 8; ++ct) {
        const int col = ct * 16 + l15;
        const float b2v = b2[col];
        #pragma unroll
        for (int i = 0; i < 4; ++i) {
            const int node = nb + w * 16 + r0 + i;
            if (node < N_NODES) {
                const float f = (acc3[ct][i] + b2v) * mk[i];
                outp[(size_t)node * DIM + col] = xg[(size_t)node * DIM + col] + f;
            }
        }
    }
}

// ---------------------------------------------------------------------------
extern "C" void kernel_launch(void* const* d_in, const int* in_sizes, int n_in,
                              void* d_out, int out_size, void* d_ws, size_t ws_size,
                              hipStream_t stream)
{
    const float* node_rep = (const float*)d_in[0];
    const float* mask     = (const float*)d_in[1];
    const float* edge_feat= (const float*)d_in[2];
    const float* Wq = (const float*)d_in[3];
    const float* bq = (const float*)d_in[4];
    const float* Wk = (const float*)d_in[5];
    const float* bk = (const float*)d_in[6];
    const float* Wv = (const float*)d_in[7];
    const float* bv = (const float*)d_in[8];
    const float* Wo = (const float*)d_in[9];
    const float* bo = (const float*)d_in[10];
    const float* ln1_s = (const float*)d_in[11];
    const float* ln1_b = (const float*)d_in[12];
    const float* ln2_s = (const float*)d_in[13];
    const float* ln2_b = (const float*)d_in[14];
    const float* W1 = (const float*)d_in[15];
    const float* b1 = (const float*)d_in[16];
    const float* W2 = (const float*)d_in[17];
    const float* b2 = (const float*)d_in[18];
    const int* senders = (const int*)d_in[19];

    float* out = (float*)d_out;
    float* xg = (float*)d_ws;                           // [N,128] f32
    float* qg = xg + (size_t)N_NODES * DIM;             // [N,128] f32
    float* og = qg + (size_t)N_NODES * DIM;             // [N,128] f32
    unsigned short* Pp   = (unsigned short*)(og + (size_t)N_NODES * DIM);  // [N,256] bf16
    unsigned short* WkvT = Pp + (size_t)N_NODES * 256;  // [256,64]
    unsigned short* WoT  = WkvT + 256 * 64;             // [128,128]
    unsigned short* W1T  = WoT + 128 * 128;             // [512,128]
    unsigned short* W2T  = W1T + 512 * 128;             // [128,512]

    hipLaunchKernelGGL(k0_prep, dim3(640), dim3(256), 0, stream,
                       Wk, Wv, Wo, W1, W2, WkvT, WoT, W1T, W2T);
    hipLaunchKernelGGL(k1_ln_q_p, dim3(N_NODES / 8), dim3(256), 0, stream,
                       node_rep, mask, ln1_s, ln1_b, Wq, bq, Wk, bk, Wv, bv,
                       xg, qg, Pp);
    hipLaunchKernelGGL(k2_attn, dim3(N_NODES / 4), dim3(256), 0, stream,
                       qg, edge_feat, Pp, WkvT, senders, og);
    hipLaunchKernelGGL(k3_ffn, dim3((N_NODES + 63) / 64), dim3(256), 0, stream,
                       og, xg, mask, WoT, bo, ln2_s, ln2_b, W1T, b1, W2T, b2, out);
}